// Round 1
// baseline (13446.700 us; speedup 1.0000x reference)
//
#include <hip/hip_runtime.h>
#include <math.h>

#define B_TOTAL 262144
#define ROWS    64
#define HID     256
#define NMEAS   27
#define IN_DIM  73
#define PI_F    3.14159265358979323846f
#define NORM_R  (500.0f / 150000.0f)
#define HSTR    65   // padded LDS row stride (floats) for [k][row] buffers

__device__ __forceinline__ float fast_sigmoid(float x) {
    return 1.0f / (1.0f + __expf(-x));
}
__device__ __forceinline__ float fast_tanh(float x) {
    // 1 - 2/(e^{2x}+1): saturates correctly for large |x|
    return 1.0f - 2.0f / (__expf(2.0f * x) + 1.0f);
}

__global__ __launch_bounds__(256, 1) void knet_kernel(
    const float* __restrict__ meas, const float* __restrict__ mask,
    const float* __restrict__ dt,   const float* __restrict__ baselines,
    const float* __restrict__ x_prev, const float* __restrict__ hx,
    const float* __restrict__ W_ih, const float* __restrict__ W_hh,
    const float* __restrict__ b_ih, const float* __restrict__ b_hh,
    const float* __restrict__ ln_g, const float* __restrict__ ln_b,
    const float* __restrict__ W1,   const float* __restrict__ b1,
    const float* __restrict__ W2,   const float* __restrict__ b2,
    const float* __restrict__ W3,   const float* __restrict__ b3,
    float* __restrict__ out)
{
    __shared__ float rnn[IN_DIM * ROWS];   // [k][row] stride 64 (73 odd-ish, conflict-free)
    __shared__ float bufA[HID * HSTR];     // hx -> f1 -> corr partials
    __shared__ float bufB[HID * HSTR];     // h_new -> h_ln -> f2

    const int tid  = threadIdx.x;
    const int w    = __builtin_amdgcn_readfirstlane(tid >> 6); // wave id 0..3 (force SGPR)
    const int lane = tid & 63;                                 // row within tile
    const int row0 = blockIdx.x * ROWS;

    // ---------------- staging ----------------
    // hx -> bufA[k][row]; consecutive tid -> consecutive k -> LDS stride 65: conflict-free
    for (int idx = tid; idx < ROWS * HID; idx += 256) {
        int r = idx >> 8;
        int k = idx & 255;
        bufA[k * HSTR + r] = hx[(size_t)(row0 + r) * HID + k];
    }
    // rnn_in = [innov(27), mask(27), dt(1), x_minus(6), baselines(12)]
    {
        const int r  = lane;
        const int gb = row0 + r;
        const float dtv = dt[gb];
        const float dts = dtv * NORM_R;
        float xp[6], xm[6];
        #pragma unroll
        for (int s = 0; s < 6; ++s) xp[s] = x_prev[(size_t)gb * 6 + s];
        xm[0] = xp[0] + dts * xp[1]; xm[1] = xp[1];
        xm[2] = xp[2] + dts * xp[3]; xm[3] = xp[3];
        xm[4] = xp[4] + dts * xp[5]; xm[5] = xp[5];
        if (w < 3) {
            float xr[6];
            #pragma unroll
            for (int s = 0; s < 6; ++s) {
                float b = (w == 0) ? 0.0f : baselines[(size_t)gb * 12 + (w - 1) * 6 + s];
                xr[s] = xm[s] - b;
            }
            float rxy = sqrtf(xr[0]*xr[0] + xr[2]*xr[2] + 1e-9f);
            float az  = atan2f(xr[2], xr[0]) * (1.0f / PI_F);
            float el  = atan2f(xr[4], rxy)   * (1.0f / PI_F);
            float rr  = sqrtf(xr[0]*xr[0] + xr[2]*xr[2] + xr[4]*xr[4] + 1e-9f);
            float y[9] = {az, el, rr, az, el, 0.0f, az, 0.0f, 0.0f};
            const bool ang[9] = {true, true, false, true, true, false, true, false, false};
            #pragma unroll
            for (int i = 0; i < 9; ++i) {
                int m = 9 * w + i;
                float ms = mask[(size_t)gb * NMEAS + m];
                float v  = meas[(size_t)gb * NMEAS + m] - y[i];
                if (ang[i]) v = v - 2.0f * rintf(v * 0.5f);  // wrap to (-1,1]
                v *= ms;
                rnn[m * ROWS + r]          = v;
                rnn[(NMEAS + m) * ROWS + r] = ms;
            }
        } else {
            rnn[54 * ROWS + r] = dtv;
            #pragma unroll
            for (int s = 0; s < 6; ++s)  rnn[(55 + s) * ROWS + r] = xm[s];
            #pragma unroll
            for (int q = 0; q < 12; ++q) rnn[(61 + q) * ROWS + r] = baselines[(size_t)gb * 12 + q];
        }
    }
    __syncthreads();

    // ---------------- GRU: wave w owns hidden j in [w*64, w*64+64) ----------------
    const int r_ = lane;
    for (int g = 0; g < 16; ++g) {
        const int j0 = w * 64 + g * 4;   // wave-uniform
        float a_r[4], a_z[4], a_gin[4], a_ghn[4];
        #pragma unroll
        for (int jj = 0; jj < 4; ++jj) {
            int j = j0 + jj;
            a_r[jj]   = b_ih[j]           + b_hh[j];
            a_z[jj]   = b_ih[HID + j]     + b_hh[HID + j];
            a_gin[jj] = b_ih[2 * HID + j];
            a_ghn[jj] = b_hh[2 * HID + j];
        }
        const float* wr = W_ih + (size_t)j0 * IN_DIM;
        const float* wz = W_ih + (size_t)(HID + j0) * IN_DIM;
        const float* wn = W_ih + (size_t)(2 * HID + j0) * IN_DIM;
        for (int k = 0; k < IN_DIM; ++k) {
            float x = rnn[k * ROWS + r_];
            #pragma unroll
            for (int jj = 0; jj < 4; ++jj) {
                a_r[jj]   = fmaf(x, wr[jj * IN_DIM + k], a_r[jj]);
                a_z[jj]   = fmaf(x, wz[jj * IN_DIM + k], a_z[jj]);
                a_gin[jj] = fmaf(x, wn[jj * IN_DIM + k], a_gin[jj]);
            }
        }
        const float* vr = W_hh + (size_t)j0 * HID;
        const float* vz = W_hh + (size_t)(HID + j0) * HID;
        const float* vn = W_hh + (size_t)(2 * HID + j0) * HID;
        for (int k = 0; k < HID; ++k) {
            float x = bufA[k * HSTR + r_];
            #pragma unroll
            for (int jj = 0; jj < 4; ++jj) {
                a_r[jj]   = fmaf(x, vr[jj * HID + k], a_r[jj]);
                a_z[jj]   = fmaf(x, vz[jj * HID + k], a_z[jj]);
                a_ghn[jj] = fmaf(x, vn[jj * HID + k], a_ghn[jj]);
            }
        }
        #pragma unroll
        for (int jj = 0; jj < 4; ++jj) {
            int j = j0 + jj;
            float rg = fast_sigmoid(a_r[jj]);
            float zg = fast_sigmoid(a_z[jj]);
            float ng = fast_tanh(a_gin[jj] + rg * a_ghn[jj]);
            float hp = bufA[j * HSTR + r_];
            bufB[j * HSTR + r_] = (1.0f - zg) * ng + zg * hp;
        }
    }
    __syncthreads();

    // ---------------- h_new -> global, LN stats ----------------
    float* hout = out + (size_t)B_TOTAL * 6;
    for (int idx = tid; idx < ROWS * HID; idx += 256) {
        int r = idx >> 8;
        int k = idx & 255;
        hout[(size_t)(row0 + r) * HID + k] = bufB[k * HSTR + r];
    }
    float sum = 0.0f, sumsq = 0.0f;
    for (int k = 0; k < HID; ++k) {
        float v = bufB[k * HSTR + r_];
        sum += v; sumsq += v * v;
    }
    float mu   = sum * (1.0f / HID);
    float var  = sumsq * (1.0f / HID) - mu * mu;
    float rstd = rsqrtf(var + 1e-5f);
    __syncthreads();
    // normalize in place; wave w handles k in [w*64, w*64+64) for all rows
    for (int k = w * 64; k < w * 64 + 64; ++k) {
        float v = bufB[k * HSTR + r_];
        bufB[k * HSTR + r_] = (v - mu) * rstd * ln_g[k] + ln_b[k];
    }
    __syncthreads();

    // ---------------- f1 = relu(W1 h_ln + b1) -> bufA ----------------
    for (int g = 0; g < 16; ++g) {
        const int j0 = w * 64 + g * 4;
        float acc[4];
        #pragma unroll
        for (int jj = 0; jj < 4; ++jj) acc[jj] = b1[j0 + jj];
        const float* p = W1 + (size_t)j0 * HID;
        for (int k = 0; k < HID; ++k) {
            float x = bufB[k * HSTR + r_];
            #pragma unroll
            for (int jj = 0; jj < 4; ++jj) acc[jj] = fmaf(x, p[jj * HID + k], acc[jj]);
        }
        #pragma unroll
        for (int jj = 0; jj < 4; ++jj)
            bufA[(j0 + jj) * HSTR + r_] = fmaxf(acc[jj], 0.0f);
    }
    __syncthreads();

    // ---------------- f2 = relu(W2 f1 + b2) -> bufB[0:128) ----------------
    for (int g = 0; g < 8; ++g) {
        const int j0 = w * 32 + g * 4;
        float acc[4];
        #pragma unroll
        for (int jj = 0; jj < 4; ++jj) acc[jj] = b2[j0 + jj];
        const float* p = W2 + (size_t)j0 * HID;
        for (int k = 0; k < HID; ++k) {
            float x = bufA[k * HSTR + r_];
            #pragma unroll
            for (int jj = 0; jj < 4; ++jj) acc[jj] = fmaf(x, p[jj * HID + k], acc[jj]);
        }
        #pragma unroll
        for (int jj = 0; jj < 4; ++jj)
            bufB[(j0 + jj) * HSTR + r_] = fmaxf(acc[jj], 0.0f);
    }
    __syncthreads();

    // ---------------- K = clip(W3 f2 + b3), correction ----------------
    // wave w takes m == w (mod 4); s unrolled statically (no dynamic reg indexing)
    {
        float cp[6];
        #pragma unroll
        for (int s = 0; s < 6; ++s) {
            float csum = 0.0f;
            for (int m = w; m < NMEAS; m += 4) {
                int c = s * NMEAS + m;          // wave-uniform
                float acc = b3[c];
                const float* p = W3 + (size_t)c * 128;
                for (int k = 0; k < 128; ++k)
                    acc = fmaf(bufB[k * HSTR + r_], p[k], acc);
                acc = fminf(fmaxf(acc, -3.0f), 3.0f);
                csum = fmaf(acc, rnn[m * ROWS + r_], csum);
            }
            cp[s] = csum;
        }
        // partial corrections -> bufA overlay (f1 dead)
        #pragma unroll
        for (int s = 0; s < 6; ++s) bufA[(w * 6 + s) * 64 + r_] = cp[s];
    }
    __syncthreads();

    if (w == 0) {
        #pragma unroll
        for (int s = 0; s < 6; ++s) {
            float t = bufA[s * 64 + r_] + bufA[(6 + s) * 64 + r_]
                    + bufA[(12 + s) * 64 + r_] + bufA[(18 + s) * 64 + r_];
            t += rnn[(55 + s) * ROWS + r_];
            t = fminf(fmaxf(t, -5.0f), 5.0f);
            out[(size_t)(row0 + r_) * 6 + s] = t;
        }
    }
}

extern "C" void kernel_launch(void* const* d_in, const int* in_sizes, int n_in,
                              void* d_out, int out_size, void* d_ws, size_t ws_size,
                              hipStream_t stream) {
    knet_kernel<<<B_TOTAL / ROWS, 256, 0, stream>>>(
        (const float*)d_in[0],  (const float*)d_in[1],  (const float*)d_in[2],
        (const float*)d_in[3],  (const float*)d_in[4],  (const float*)d_in[5],
        (const float*)d_in[6],  (const float*)d_in[7],  (const float*)d_in[8],
        (const float*)d_in[9],  (const float*)d_in[10], (const float*)d_in[11],
        (const float*)d_in[12], (const float*)d_in[13], (const float*)d_in[14],
        (const float*)d_in[15], (const float*)d_in[16], (const float*)d_in[17],
        (float*)d_out);
}

// Round 2
// 1150.572 us; speedup vs baseline: 11.6870x; 11.6870x over previous
//
#include <hip/hip_runtime.h>
#include <math.h>

#define B_TOTAL  262144
#define ROWS     128
#define NWG      (B_TOTAL/ROWS)   // 2048
#define NTHR     512
#define PI_F     3.14159265358979323846f
#define NORM_R   (500.0f/150000.0f)

typedef float  f32x4  __attribute__((ext_vector_type(4)));
typedef short  bf16x8 __attribute__((ext_vector_type(8)));

// ---- bf16 weight workspace layout (ushort units) ----
#define SRZ 352   // [512][352]: k<73 = W_ih rows 0..511 ; k 96..351 = W_hh rows 0..511 ; 73..95 zero
#define SNI 96    // [256][96]:  W_ih rows 512..767 (n-gate input), k>=73 zero
#define SNH 256   // [256][256]: W_hh rows 512..767
#define SW1 256
#define SW2 256
#define SW3 128   // [192][128]: rows >=162 zero
#define OFF_RZ 0
#define OFF_NI (OFF_RZ + 512*SRZ)
#define OFF_NH (OFF_NI + 256*SNI)
#define OFF_W1 (OFF_NH + 256*SNH)
#define OFF_W2 (OFF_W1 + 256*SW1)
#define OFF_W3 (OFF_W2 + 128*SW2)
#define W_TOTAL (OFF_W3 + 192*SW3)  // 393216 ushort = 768 KiB

// ---- LDS layout (byte offsets) ----
#define RSTRIDE 104                       // bf16 units; 104*2=208B: 52w = 20 mod 32 -> conflict-free
#define LDS_HB   (ROWS*RSTRIDE*2)         // Rbuf: [128][104] bf16 (rnn_in, k padded to 96)
#define LDS_F1   (LDS_HB + ROWS*256*2)    // Hb:   [128][256] bf16 swizzled (hx -> h_ln -> F2 overlay)
#define LDS_XMC  (LDS_F1 + ROWS*256*2)    // F1:   [128][256] bf16 swizzled (h_new -> f1)
#define LDS_TOTAL (LDS_XMC + ROWS*6*4)    // xmc:  [128][6] f32 (x_minus + correction accum)

__device__ __forceinline__ ushort f2bf(float f){                 // fp32 -> bf16 RNE
    union { float f; unsigned u; } v; v.f = f;
    unsigned r = v.u + 0x7FFFu + ((v.u >> 16) & 1u);
    return (ushort)(r >> 16);
}
__device__ __forceinline__ float b2f(ushort u){
    union { unsigned u; float f; } v; v.u = ((unsigned)u) << 16;
    return v.f;
}
__device__ __forceinline__ float sigm(float x){ return 1.0f/(1.0f+__expf(-x)); }
__device__ __forceinline__ float tanh_(float x){ return 1.0f - 2.0f/(__expf(2.0f*x)+1.0f); }
// XOR swizzle for [128][256] bf16 LDS tiles: 16B-block swizzle, conflict-free A-frag reads
__device__ __forceinline__ int swzb(int row, int k){
    return ((row<<9) + (k<<1)) ^ ((row&7)<<4);
}

__global__ void prep_weights(const float* __restrict__ W_ih, const float* __restrict__ W_hh,
                             const float* __restrict__ W1, const float* __restrict__ W2,
                             const float* __restrict__ W3, ushort* __restrict__ ws)
{
    int id = blockIdx.x*256 + threadIdx.x;
    if (id >= W_TOTAL) return;
    float v = 0.0f;
    if (id < OFF_NI) {
        int t = id; int n = t / SRZ, k = t - n*SRZ;
        if (k < 73) v = W_ih[n*73 + k];
        else if (k >= 96) v = W_hh[n*256 + (k-96)];
    } else if (id < OFF_NH) {
        int t = id - OFF_NI; int n = t / SNI, k = t - n*SNI;
        if (k < 73) v = W_ih[(512+n)*73 + k];
    } else if (id < OFF_W1) {
        int t = id - OFF_NH; int n = t >> 8, k = t & 255;
        v = W_hh[(512+n)*256 + k];
    } else if (id < OFF_W2) {
        int t = id - OFF_W1; int n = t >> 8, k = t & 255;
        v = W1[n*256 + k];
    } else if (id < OFF_W3) {
        int t = id - OFF_W2; int n = t >> 8, k = t & 255;
        v = W2[n*256 + k];
    } else {
        int t = id - OFF_W3; int n = t >> 7, k = t & 127;
        if (n < 162) v = W3[n*128 + k];
    }
    ws[id] = f2bf(v);
}

__global__ __launch_bounds__(NTHR, 2) void knet_mfma(
    const float* __restrict__ meas, const float* __restrict__ mask,
    const float* __restrict__ dt,   const float* __restrict__ baselines,
    const float* __restrict__ x_prev, const float* __restrict__ hx,
    const float* __restrict__ b_ih, const float* __restrict__ b_hh,
    const float* __restrict__ ln_g, const float* __restrict__ ln_b,
    const float* __restrict__ b1,   const float* __restrict__ b2,
    const float* __restrict__ b3,
    const ushort* __restrict__ ws,
    float* __restrict__ out)
{
    extern __shared__ char smem[];
    ushort* Rb  = (ushort*)smem;                 // [128][104] bf16
    char*   Hb  = smem + LDS_HB;                 // [128][256] bf16 swizzled
    char*   F1  = smem + LDS_F1;                 // [128][256] bf16 swizzled
    float*  xmc = (float*)(smem + LDS_XMC);      // [128][6] f32

    const int tid  = threadIdx.x;
    const int w    = __builtin_amdgcn_readfirstlane(tid >> 6);
    const int nq   = w & 3;          // N-quarter
    const int mh   = w >> 2;         // M-half
    const int lane = tid & 63;
    const int lr   = lane & 15;      // A: row-in-frag / B: col-in-frag
    const int lk   = lane >> 4;
    const int lk8  = lk * 8;         // k offset in frag
    const int row0 = blockIdx.x * ROWS;
    const int mrow = mh*64 + lr;
    float* hout = out + (size_t)B_TOTAL*6;

    // ================= stage =================
    {
        const int part = tid >> 7;           // wave-uniform
        const int row  = tid & 127;
        const int gb   = row0 + row;
        const float dtv = dt[gb];
        const float dts = dtv * NORM_R;
        float xp[6], xm[6];
        #pragma unroll
        for (int s = 0; s < 6; ++s) xp[s] = x_prev[(size_t)gb*6 + s];
        xm[0] = xp[0] + dts*xp[1]; xm[1] = xp[1];
        xm[2] = xp[2] + dts*xp[3]; xm[3] = xp[3];
        xm[4] = xp[4] + dts*xp[5]; xm[5] = xp[5];
        if (part < 3) {
            float xr[6];
            #pragma unroll
            for (int s = 0; s < 6; ++s) {
                float b = (part == 0) ? 0.0f : baselines[(size_t)gb*12 + (part-1)*6 + s];
                xr[s] = xm[s] - b;
            }
            float rxy = sqrtf(xr[0]*xr[0] + xr[2]*xr[2] + 1e-9f);
            float azv = atan2f(xr[2], xr[0]) * (1.0f/PI_F);
            float elv = atan2f(xr[4], rxy)   * (1.0f/PI_F);
            float rrv = sqrtf(xr[0]*xr[0] + xr[2]*xr[2] + xr[4]*xr[4] + 1e-9f);
            float y[9] = {azv, elv, rrv, azv, elv, 0.0f, azv, 0.0f, 0.0f};
            const bool ang[9] = {true,true,false,true,true,false,true,false,false};
            #pragma unroll
            for (int i = 0; i < 9; ++i) {
                int m = part*9 + i;
                float ms = mask[(size_t)gb*27 + m];
                float v  = meas[(size_t)gb*27 + m] - y[i];
                if (ang[i]) v = v - 2.0f*rintf(v*0.5f);
                v *= ms;
                Rb[row*RSTRIDE + m]      = f2bf(v);
                Rb[row*RSTRIDE + 27 + m] = f2bf(ms);
            }
        } else {
            Rb[row*RSTRIDE + 54] = f2bf(dtv);
            #pragma unroll
            for (int s = 0; s < 6; ++s) Rb[row*RSTRIDE + 55 + s] = f2bf(xm[s]);
            #pragma unroll
            for (int q = 0; q < 12; ++q) Rb[row*RSTRIDE + 61 + q] = f2bf(baselines[(size_t)gb*12 + q]);
            #pragma unroll
            for (int k = 73; k < 96; ++k) Rb[row*RSTRIDE + k] = 0;  // zero pads (avoid NaN*0)
            #pragma unroll
            for (int s = 0; s < 6; ++s) xmc[row*6 + s] = xm[s];
        }
        // hx -> Hb (bf16, swizzled), 8 chunks of 8 per thread
        const size_t hbase = (size_t)row0 * 256;
        #pragma unroll
        for (int ii = 0; ii < 8; ++ii) {
            int cid = tid + ii*NTHR;
            int r  = cid >> 5;
            int k0 = (cid & 31) << 3;
            const float4* p = (const float4*)(hx + hbase + (size_t)r*256 + k0);
            float4 u = p[0], v2 = p[1];
            bf16x8 o;
            o[0]=(short)f2bf(u.x);  o[1]=(short)f2bf(u.y);  o[2]=(short)f2bf(u.z);  o[3]=(short)f2bf(u.w);
            o[4]=(short)f2bf(v2.x); o[5]=(short)f2bf(v2.y); o[6]=(short)f2bf(v2.z); o[7]=(short)f2bf(v2.w);
            *(bf16x8*)(Hb + swzb(r, k0)) = o;
        }
    }
    __syncthreads();

    // ================= GRU r,z (concat-K GEMM, N=512) =================
    f32x4 ar[4][4], az_[4][4];
    #pragma unroll
    for (int i = 0; i < 4; ++i)
        #pragma unroll
        for (int j = 0; j < 4; ++j) { ar[i][j] = (f32x4){0,0,0,0}; az_[i][j] = (f32x4){0,0,0,0}; }

    for (int kb = 0; kb < 11; ++kb) {
        bf16x8 a[4];
        if (kb < 3) {
            #pragma unroll
            for (int i = 0; i < 4; ++i)
                a[i] = *(const bf16x8*)(Rb + (mrow + i*16)*RSTRIDE + kb*32 + lk8);
        } else {
            #pragma unroll
            for (int i = 0; i < 4; ++i)
                a[i] = *(const bf16x8*)(Hb + swzb(mrow + i*16, (kb-3)*32 + lk8));
        }
        #pragma unroll
        for (int j = 0; j < 4; ++j) {
            bf16x8 br = *(const bf16x8*)(ws + OFF_RZ + (size_t)((nq*4+j)*16 + lr)*SRZ + kb*32 + lk8);
            bf16x8 bz = *(const bf16x8*)(ws + OFF_RZ + (size_t)((16+nq*4+j)*16 + lr)*SRZ + kb*32 + lk8);
            #pragma unroll
            for (int i = 0; i < 4; ++i) {
                ar[i][j]  = __builtin_amdgcn_mfma_f32_16x16x32_bf16(a[i], br, ar[i][j], 0,0,0);
                az_[i][j] = __builtin_amdgcn_mfma_f32_16x16x32_bf16(a[i], bz, az_[i][j], 0,0,0);
            }
        }
    }
    #pragma unroll
    for (int j = 0; j < 4; ++j) {
        int c = (nq*4+j)*16 + lr;
        float brv = b_ih[c] + b_hh[c];
        float bzv = b_ih[256+c] + b_hh[256+c];
        #pragma unroll
        for (int i = 0; i < 4; ++i)
            #pragma unroll
            for (int e = 0; e < 4; ++e) {
                ar[i][j][e]  = sigm(ar[i][j][e] + brv);   // r gate
                az_[i][j][e] = sigm(az_[i][j][e] + bzv);  // z gate
            }
    }

    // ================= GRU n gate (4 N-quarters) + h_new =================
    #pragma unroll
    for (int j = 0; j < 4; ++j) {
        f32x4 gi[4], gh[4];
        #pragma unroll
        for (int i = 0; i < 4; ++i) { gi[i] = (f32x4){0,0,0,0}; gh[i] = (f32x4){0,0,0,0}; }
        for (int kb = 0; kb < 3; ++kb) {
            bf16x8 b = *(const bf16x8*)(ws + OFF_NI + (size_t)(nq*64 + j*16 + lr)*SNI + kb*32 + lk8);
            #pragma unroll
            for (int i = 0; i < 4; ++i) {
                bf16x8 a = *(const bf16x8*)(Rb + (mrow + i*16)*RSTRIDE + kb*32 + lk8);
                gi[i] = __builtin_amdgcn_mfma_f32_16x16x32_bf16(a, b, gi[i], 0,0,0);
            }
        }
        for (int kb = 0; kb < 8; ++kb) {
            bf16x8 b = *(const bf16x8*)(ws + OFF_NH + (size_t)(nq*64 + j*16 + lr)*SNH + kb*32 + lk8);
            #pragma unroll
            for (int i = 0; i < 4; ++i) {
                bf16x8 a = *(const bf16x8*)(Hb + swzb(mrow + i*16, kb*32 + lk8));
                gh[i] = __builtin_amdgcn_mfma_f32_16x16x32_bf16(a, b, gh[i], 0,0,0);
            }
        }
        int c = (nq*4+j)*16 + lr;
        float binv = b_ih[512+c], bhnv = b_hh[512+c];
        #pragma unroll
        for (int i = 0; i < 4; ++i)
            #pragma unroll
            for (int e = 0; e < 4; ++e) {
                int row = mh*64 + i*16 + lk*4 + e;
                float hxv = b2f(*(const ushort*)(Hb + swzb(row, c)));
                float ng = tanh_(gi[i][e] + binv + ar[i][j][e]*(gh[i][e] + bhnv));
                float zg = az_[i][j][e];
                float hn = (1.0f - zg)*ng + zg*hxv;
                hout[(size_t)(row0+row)*256 + c] = hn;                 // global h_new (fp32)
                *(ushort*)(F1 + swzb(row, c)) = f2bf(hn);              // LDS h_new (bf16)
            }
    }
    __syncthreads();

    // ================= LayerNorm: F1(h_new) -> Hb(h_ln) =================
    {
        int row = tid >> 2, q = tid & 3;
        float vals[64];
        float sum = 0.0f, sq = 0.0f;
        #pragma unroll
        for (int jx = 0; jx < 8; ++jx) {
            bf16x8 vchunk = *(const bf16x8*)(F1 + swzb(row, q*64 + jx*8));
            #pragma unroll
            for (int e = 0; e < 8; ++e) {
                float f = b2f((ushort)vchunk[e]);
                vals[jx*8+e] = f; sum += f; sq += f*f;
            }
        }
        sum += __shfl_xor(sum, 1); sum += __shfl_xor(sum, 2);
        sq  += __shfl_xor(sq, 1);  sq  += __shfl_xor(sq, 2);
        float mu   = sum * (1.0f/256.0f);
        float rstd = rsqrtf(sq*(1.0f/256.0f) - mu*mu + 1e-5f);
        #pragma unroll
        for (int jx = 0; jx < 8; ++jx) {
            bf16x8 o;
            #pragma unroll
            for (int e = 0; e < 8; ++e) {
                int c = q*64 + jx*8 + e;
                float f = (vals[jx*8+e] - mu)*rstd*ln_g[c] + ln_b[c];
                o[e] = (short)f2bf(f);
            }
            *(bf16x8*)(Hb + swzb(row, q*64 + jx*8)) = o;
        }
    }
    __syncthreads();

    // ================= f1 = relu(W1 h_ln + b1): Hb -> F1 =================
    {
        f32x4 c2[4][4];
        #pragma unroll
        for (int i = 0; i < 4; ++i)
            #pragma unroll
            for (int j = 0; j < 4; ++j) c2[i][j] = (f32x4){0,0,0,0};
        for (int kb = 0; kb < 8; ++kb) {
            bf16x8 a[4];
            #pragma unroll
            for (int i = 0; i < 4; ++i)
                a[i] = *(const bf16x8*)(Hb + swzb(mrow + i*16, kb*32 + lk8));
            #pragma unroll
            for (int j = 0; j < 4; ++j) {
                bf16x8 b = *(const bf16x8*)(ws + OFF_W1 + (size_t)(nq*64 + j*16 + lr)*SW1 + kb*32 + lk8);
                #pragma unroll
                for (int i = 0; i < 4; ++i)
                    c2[i][j] = __builtin_amdgcn_mfma_f32_16x16x32_bf16(a[i], b, c2[i][j], 0,0,0);
            }
        }
        #pragma unroll
        for (int j = 0; j < 4; ++j) {
            int c = nq*64 + j*16 + lr;
            float bv = b1[c];
            #pragma unroll
            for (int i = 0; i < 4; ++i)
                #pragma unroll
                for (int e = 0; e < 4; ++e) {
                    int row = mh*64 + i*16 + lk*4 + e;
                    *(ushort*)(F1 + swzb(row, c)) = f2bf(fmaxf(c2[i][j][e] + bv, 0.0f));
                }
        }
    }
    __syncthreads();

    // ================= f2 = relu(W2 f1 + b2): F1 -> F2 (overlay on Hb) =================
    ushort* F2 = (ushort*)Hb;   // [128][136] bf16, padded stride
    {
        f32x4 c3[4][2];
        #pragma unroll
        for (int i = 0; i < 4; ++i)
            #pragma unroll
            for (int j = 0; j < 2; ++j) c3[i][j] = (f32x4){0,0,0,0};
        for (int kb = 0; kb < 8; ++kb) {
            bf16x8 a[4];
            #pragma unroll
            for (int i = 0; i < 4; ++i)
                a[i] = *(const bf16x8*)(F1 + swzb(mrow + i*16, kb*32 + lk8));
            #pragma unroll
            for (int j = 0; j < 2; ++j) {
                bf16x8 b = *(const bf16x8*)(ws + OFF_W2 + (size_t)(nq*32 + j*16 + lr)*SW2 + kb*32 + lk8);
                #pragma unroll
                for (int i = 0; i < 4; ++i)
                    c3[i][j] = __builtin_amdgcn_mfma_f32_16x16x32_bf16(a[i], b, c3[i][j], 0,0,0);
            }
        }
        #pragma unroll
        for (int j = 0; j < 2; ++j) {
            int c = nq*32 + j*16 + lr;
            float bv = b2[c];
            #pragma unroll
            for (int i = 0; i < 4; ++i)
                #pragma unroll
                for (int e = 0; e < 4; ++e) {
                    int row = mh*64 + i*16 + lk*4 + e;
                    F2[row*136 + c] = f2bf(fmaxf(c3[i][j][e] + bv, 0.0f));
                }
        }
    }
    __syncthreads();

    // ================= K = clip(W3 f2 + b3), correction einsum =================
    {
        f32x4 c4[4][3];
        #pragma unroll
        for (int i = 0; i < 4; ++i)
            #pragma unroll
            for (int j = 0; j < 3; ++j) c4[i][j] = (f32x4){0,0,0,0};
        const int nfb = nq*3;   // 0,3,6,9 -> cols 0..191 (>=162 masked)
        for (int kb = 0; kb < 4; ++kb) {
            bf16x8 a[4];
            #pragma unroll
            for (int i = 0; i < 4; ++i)
                a[i] = *(const bf16x8*)(F2 + (mrow + i*16)*136 + kb*32 + lk8);
            #pragma unroll
            for (int j = 0; j < 3; ++j) {
                bf16x8 b = *(const bf16x8*)(ws + OFF_W3 + (size_t)((nfb+j)*16 + lr)*SW3 + kb*32 + lk8);
                #pragma unroll
                for (int i = 0; i < 4; ++i)
                    c4[i][j] = __builtin_amdgcn_mfma_f32_16x16x32_bf16(a[i], b, c4[i][j], 0,0,0);
            }
        }
        #pragma unroll
        for (int j = 0; j < 3; ++j) {
            int col = (nfb+j)*16 + lr;
            if (col < 162) {
                int s = col / 27, m = col - s*27;
                float bv = b3[col];
                #pragma unroll
                for (int i = 0; i < 4; ++i)
                    #pragma unroll
                    for (int e = 0; e < 4; ++e) {
                        int row = mh*64 + i*16 + lk*4 + e;
                        float K  = fminf(fmaxf(c4[i][j][e] + bv, -3.0f), 3.0f);
                        float iv = b2f(Rb[row*RSTRIDE + m]);   // masked innov (bf16)
                        atomicAdd(&xmc[row*6 + s], K*iv);
                    }
            }
        }
    }
    __syncthreads();

    for (int t = tid; t < ROWS*6; t += NTHR) {
        int row = t / 6, s = t - row*6;
        float v = fminf(fmaxf(xmc[t], -5.0f), 5.0f);
        out[(size_t)(row0+row)*6 + s] = v;
    }
}

extern "C" void kernel_launch(void* const* d_in, const int* in_sizes, int n_in,
                              void* d_out, int out_size, void* d_ws, size_t ws_size,
                              hipStream_t stream) {
    const float* meas      = (const float*)d_in[0];
    const float* mask      = (const float*)d_in[1];
    const float* dtv       = (const float*)d_in[2];
    const float* baselines = (const float*)d_in[3];
    const float* x_prev    = (const float*)d_in[4];
    const float* hx        = (const float*)d_in[5];
    const float* W_ih      = (const float*)d_in[6];
    const float* W_hh      = (const float*)d_in[7];
    const float* b_ih      = (const float*)d_in[8];
    const float* b_hh      = (const float*)d_in[9];
    const float* ln_g      = (const float*)d_in[10];
    const float* ln_b      = (const float*)d_in[11];
    const float* W1        = (const float*)d_in[12];
    const float* b1        = (const float*)d_in[13];
    const float* W2        = (const float*)d_in[14];
    const float* b2        = (const float*)d_in[15];
    const float* W3        = (const float*)d_in[16];
    const float* b3        = (const float*)d_in[17];
    ushort* wsb = (ushort*)d_ws;
    float* outp = (float*)d_out;

    prep_weights<<<(W_TOTAL + 255)/256, 256, 0, stream>>>(W_ih, W_hh, W1, W2, W3, wsb);
    knet_mfma<<<NWG, NTHR, LDS_TOTAL, stream>>>(
        meas, mask, dtv, baselines, x_prev, hx,
        b_ih, b_hh, ln_g, ln_b, b1, b2, b3, wsb, outp);
}

// Round 3
// 1097.473 us; speedup vs baseline: 12.2524x; 1.0484x over previous
//
#include <hip/hip_runtime.h>
#include <math.h>

#define B_TOTAL  262144
#define ROWS     64
#define NWG      (B_TOTAL/ROWS)   // 4096
#define NTHR     512
#define PI_F     3.14159265358979323846f
#define NORM_R   (500.0f/150000.0f)

typedef float  f32x4  __attribute__((ext_vector_type(4)));
typedef short  bf16x8 __attribute__((ext_vector_type(8)));

// ---- bf16 weight workspace layout (ushort units) ----
#define SRZ 352   // [512][352]: k<73 = W_ih rows 0..511 ; k 96..351 = W_hh rows 0..511 ; 73..95 zero
#define SNI 96    // [256][96]:  W_ih rows 512..767 (n-gate input), k>=73 zero
#define SNH 256   // [256][256]: W_hh rows 512..767
#define SW1 256
#define SW2 256
#define SW3 128   // [192][128]: rows >=162 zero
#define OFF_RZ 0
#define OFF_NI (OFF_RZ + 512*SRZ)
#define OFF_NH (OFF_NI + 256*SNI)
#define OFF_W1 (OFF_NH + 256*SNH)
#define OFF_W2 (OFF_W1 + 256*SW1)
#define OFF_W3 (OFF_W2 + 128*SW2)
#define W_TOTAL (OFF_W3 + 192*SW3)  // 393216 ushort = 768 KiB

// ---- LDS layout (byte offsets), ROWS=64 ----
#define RSTRIDE 104                        // bf16 units; 208B rows: 52 dw = 20 mod 32
#define LDS_HB   (ROWS*RSTRIDE*2)          // Rb: [64][104] bf16
#define LDS_F1   (LDS_HB + ROWS*256*2)     // Hb: [64][256] bf16 swizzled (hx -> h_ln -> F2 overlay)
#define LDS_XMC  (LDS_F1 + ROWS*256*2)     // F1: [64][256] bf16 swizzled (h_new -> f1)
#define LDS_TOTAL (LDS_XMC + ROWS*6*4)     // xmc: [64][6] f32   => 80384 B (2 WG/CU)

__device__ __forceinline__ ushort f2bf(float f){
    union { float f; unsigned u; } v; v.f = f;
    unsigned r = v.u + 0x7FFFu + ((v.u >> 16) & 1u);
    return (ushort)(r >> 16);
}
__device__ __forceinline__ float b2f(ushort u){
    union { unsigned u; float f; } v; v.u = ((unsigned)u) << 16;
    return v.f;
}
__device__ __forceinline__ float sigm(float x){ return 1.0f/(1.0f+__expf(-x)); }
__device__ __forceinline__ float tanh_(float x){ return 1.0f - 2.0f/(__expf(2.0f*x)+1.0f); }
__device__ __forceinline__ int swzb(int row, int k){          // [*][256] bf16, 16B-XOR swizzle
    return ((row<<9) + (k<<1)) ^ ((row&7)<<4);
}

__global__ void prep_weights(const float* __restrict__ W_ih, const float* __restrict__ W_hh,
                             const float* __restrict__ W1, const float* __restrict__ W2,
                             const float* __restrict__ W3, ushort* __restrict__ ws)
{
    int id = blockIdx.x*256 + threadIdx.x;
    if (id >= W_TOTAL) return;
    float v = 0.0f;
    if (id < OFF_NI) {
        int t = id; int n = t / SRZ, k = t - n*SRZ;
        if (k < 73) v = W_ih[n*73 + k];
        else if (k >= 96) v = W_hh[n*256 + (k-96)];
    } else if (id < OFF_NH) {
        int t = id - OFF_NI; int n = t / SNI, k = t - n*SNI;
        if (k < 73) v = W_ih[(512+n)*73 + k];
    } else if (id < OFF_W1) {
        int t = id - OFF_NH; int n = t >> 8, k = t & 255;
        v = W_hh[(512+n)*256 + k];
    } else if (id < OFF_W2) {
        int t = id - OFF_W1; int n = t >> 8, k = t & 255;
        v = W1[n*256 + k];
    } else if (id < OFF_W3) {
        int t = id - OFF_W2; int n = t >> 8, k = t & 255;
        v = W2[n*256 + k];
    } else {
        int t = id - OFF_W3; int n = t >> 7, k = t & 127;
        if (n < 162) v = W3[n*128 + k];
    }
    ws[id] = f2bf(v);
}

// one gate of the GRU input+hidden GEMM (K=352 concat), depth-1 B prefetch
__device__ __forceinline__ void pass_rz(const ushort* __restrict__ wsb,
        const ushort* __restrict__ Rb, const char* __restrict__ Hb,
        int colbase /* gate*256 + nq*64 + lr */, int mrow, int lk8, f32x4 acc[2][4])
{
    const ushort* Bp = wsb + OFF_RZ + (size_t)colbase*SRZ + lk8;
    bf16x8 bc[4], bn[4];
    #pragma unroll
    for (int j = 0; j < 4; ++j) bc[j] = *(const bf16x8*)(Bp + j*16*SRZ);
    #pragma unroll
    for (int kb = 0; kb < 11; ++kb) {
        if (kb < 10) {
            #pragma unroll
            for (int j = 0; j < 4; ++j) bn[j] = *(const bf16x8*)(Bp + j*16*SRZ + (kb+1)*32);
        }
        bf16x8 a0, a1;
        if (kb < 3) {
            a0 = *(const bf16x8*)(Rb + (mrow     )*RSTRIDE + kb*32 + lk8);
            a1 = *(const bf16x8*)(Rb + (mrow + 16)*RSTRIDE + kb*32 + lk8);
        } else {
            a0 = *(const bf16x8*)(Hb + swzb(mrow,      (kb-3)*32 + lk8));
            a1 = *(const bf16x8*)(Hb + swzb(mrow + 16, (kb-3)*32 + lk8));
        }
        #pragma unroll
        for (int j = 0; j < 4; ++j) {
            acc[0][j] = __builtin_amdgcn_mfma_f32_16x16x32_bf16(a0, bc[j], acc[0][j], 0,0,0);
            acc[1][j] = __builtin_amdgcn_mfma_f32_16x16x32_bf16(a1, bc[j], acc[1][j], 0,0,0);
        }
        #pragma unroll
        for (int j = 0; j < 4; ++j) bc[j] = bn[j];
    }
}

__global__ __launch_bounds__(NTHR, 4) void knet_mfma(
    const float* __restrict__ meas, const float* __restrict__ mask,
    const float* __restrict__ dt,   const float* __restrict__ baselines,
    const float* __restrict__ x_prev, const float* __restrict__ hx,
    const float* __restrict__ b_ih, const float* __restrict__ b_hh,
    const float* __restrict__ ln_g, const float* __restrict__ ln_b,
    const float* __restrict__ b1,   const float* __restrict__ b2,
    const float* __restrict__ b3,
    const ushort* __restrict__ ws,
    float* __restrict__ out)
{
    extern __shared__ char smem[];
    ushort* Rb  = (ushort*)smem;                 // [64][104] bf16
    char*   Hb  = smem + LDS_HB;                 // [64][256] bf16 swizzled
    char*   F1  = smem + LDS_F1;                 // [64][256] bf16 swizzled
    float*  xmc = (float*)(smem + LDS_XMC);      // [64][6] f32

    const int tid  = threadIdx.x;
    const int w    = __builtin_amdgcn_readfirstlane(tid >> 6);
    const int nq   = w & 3;          // N-quarter
    const int mh   = w >> 2;         // M-half (rows mh*32..mh*32+31)
    const int lane = tid & 63;
    const int lr   = lane & 15;
    const int lk   = lane >> 4;
    const int lk8  = lk * 8;
    const int row0 = blockIdx.x * ROWS;
    const int mrow = mh*32 + lr;
    float* hout = out + (size_t)B_TOTAL*6;

    // ================= stage =================
    {
        const int part = w;              // wave id 0..7
        const int row  = lane;
        const int gb   = row0 + row;
        if (part < 4) {
            const float dtv = dt[gb];
            const float dts = dtv * NORM_R;
            float xp[6], xm[6];
            #pragma unroll
            for (int s = 0; s < 6; ++s) xp[s] = x_prev[(size_t)gb*6 + s];
            xm[0] = xp[0] + dts*xp[1]; xm[1] = xp[1];
            xm[2] = xp[2] + dts*xp[3]; xm[3] = xp[3];
            xm[4] = xp[4] + dts*xp[5]; xm[5] = xp[5];
            if (part < 3) {
                float xr[6];
                #pragma unroll
                for (int s = 0; s < 6; ++s) {
                    float b = (part == 0) ? 0.0f : baselines[(size_t)gb*12 + (part-1)*6 + s];
                    xr[s] = xm[s] - b;
                }
                float rxy = sqrtf(xr[0]*xr[0] + xr[2]*xr[2] + 1e-9f);
                float azv = atan2f(xr[2], xr[0]) * (1.0f/PI_F);
                float elv = atan2f(xr[4], rxy)   * (1.0f/PI_F);
                float rrv = sqrtf(xr[0]*xr[0] + xr[2]*xr[2] + xr[4]*xr[4] + 1e-9f);
                float y[9] = {azv, elv, rrv, azv, elv, 0.0f, azv, 0.0f, 0.0f};
                const bool ang[9] = {true,true,false,true,true,false,true,false,false};
                #pragma unroll
                for (int i = 0; i < 9; ++i) {
                    int m = part*9 + i;
                    float ms = mask[(size_t)gb*27 + m];
                    float v  = meas[(size_t)gb*27 + m] - y[i];
                    if (ang[i]) v = v - 2.0f*rintf(v*0.5f);
                    v *= ms;
                    Rb[row*RSTRIDE + m]      = f2bf(v);
                    Rb[row*RSTRIDE + 27 + m] = f2bf(ms);
                }
            } else {
                Rb[row*RSTRIDE + 54] = f2bf(dtv);
                #pragma unroll
                for (int s = 0; s < 6; ++s) Rb[row*RSTRIDE + 55 + s] = f2bf(xm[s]);
                #pragma unroll
                for (int q = 0; q < 12; ++q) Rb[row*RSTRIDE + 61 + q] = f2bf(baselines[(size_t)gb*12 + q]);
                #pragma unroll
                for (int k = 73; k < 96; ++k) Rb[row*RSTRIDE + k] = 0;
                #pragma unroll
                for (int s = 0; s < 6; ++s) xmc[row*6 + s] = xm[s];
            }
        }
        // hx -> Hb (bf16 swizzled): 64 rows x 256 cols, 4 chunks of 8 per thread
        const size_t hbase = (size_t)row0 * 256;
        #pragma unroll
        for (int ii = 0; ii < 4; ++ii) {
            int cid = tid + ii*NTHR;
            int r  = cid >> 5;
            int k0 = (cid & 31) << 3;
            const float4* p = (const float4*)(hx + hbase + (size_t)r*256 + k0);
            float4 u = p[0], v2 = p[1];
            bf16x8 o;
            o[0]=(short)f2bf(u.x);  o[1]=(short)f2bf(u.y);  o[2]=(short)f2bf(u.z);  o[3]=(short)f2bf(u.w);
            o[4]=(short)f2bf(v2.x); o[5]=(short)f2bf(v2.y); o[6]=(short)f2bf(v2.z); o[7]=(short)f2bf(v2.w);
            *(bf16x8*)(Hb + swzb(r, k0)) = o;
        }
    }
    __syncthreads();

    // ================= GRU r-pass then z-pass =================
    f32x4 ar[2][4], az_[2][4];
    #pragma unroll
    for (int i = 0; i < 2; ++i)
        #pragma unroll
        for (int j = 0; j < 4; ++j) { ar[i][j] = (f32x4){0,0,0,0}; az_[i][j] = (f32x4){0,0,0,0}; }
    pass_rz(ws, Rb, Hb, /*r*/       nq*64 + lr, mrow, lk8, ar);
    pass_rz(ws, Rb, Hb, /*z*/ 256 + nq*64 + lr, mrow, lk8, az_);
    #pragma unroll
    for (int j = 0; j < 4; ++j) {
        int c = nq*64 + j*16 + lr;
        float brv = b_ih[c] + b_hh[c];
        float bzv = b_ih[256+c] + b_hh[256+c];
        #pragma unroll
        for (int i = 0; i < 2; ++i)
            #pragma unroll
            for (int e = 0; e < 4; ++e) {
                ar[i][j][e]  = sigm(ar[i][j][e] + brv);
                az_[i][j][e] = sigm(az_[i][j][e] + bzv);
            }
    }

    // ================= GRU n gate (per 16-col chunk) + h_new -> F1 =================
    #pragma unroll
    for (int j = 0; j < 4; ++j) {
        const int c = nq*64 + j*16 + lr;
        f32x4 gi[2] = {(f32x4){0,0,0,0},(f32x4){0,0,0,0}};
        f32x4 gh[2] = {(f32x4){0,0,0,0},(f32x4){0,0,0,0}};
        {   // gi over rnn_in (kb 0..2), depth-1 prefetch
            const ushort* Bp = ws + OFF_NI + (size_t)c*SNI + lk8;
            bf16x8 bc = *(const bf16x8*)(Bp), bn;
            #pragma unroll
            for (int kb = 0; kb < 3; ++kb) {
                if (kb < 2) bn = *(const bf16x8*)(Bp + (kb+1)*32);
                bf16x8 a0 = *(const bf16x8*)(Rb + (mrow     )*RSTRIDE + kb*32 + lk8);
                bf16x8 a1 = *(const bf16x8*)(Rb + (mrow + 16)*RSTRIDE + kb*32 + lk8);
                gi[0] = __builtin_amdgcn_mfma_f32_16x16x32_bf16(a0, bc, gi[0], 0,0,0);
                gi[1] = __builtin_amdgcn_mfma_f32_16x16x32_bf16(a1, bc, gi[1], 0,0,0);
                bc = bn;
            }
        }
        {   // gh over hx (kb 0..7), depth-1 prefetch
            const ushort* Bp = ws + OFF_NH + (size_t)c*SNH + lk8;
            bf16x8 bc = *(const bf16x8*)(Bp), bn;
            #pragma unroll
            for (int kb = 0; kb < 8; ++kb) {
                if (kb < 7) bn = *(const bf16x8*)(Bp + (kb+1)*32);
                bf16x8 a0 = *(const bf16x8*)(Hb + swzb(mrow,      kb*32 + lk8));
                bf16x8 a1 = *(const bf16x8*)(Hb + swzb(mrow + 16, kb*32 + lk8));
                gh[0] = __builtin_amdgcn_mfma_f32_16x16x32_bf16(a0, bc, gh[0], 0,0,0);
                gh[1] = __builtin_amdgcn_mfma_f32_16x16x32_bf16(a1, bc, gh[1], 0,0,0);
                bc = bn;
            }
        }
        float binv = b_ih[512+c], bhnv = b_hh[512+c];
        #pragma unroll
        for (int i = 0; i < 2; ++i)
            #pragma unroll
            for (int e = 0; e < 4; ++e) {
                int row = mh*32 + i*16 + lk*4 + e;
                float hxv = b2f(*(const ushort*)(Hb + swzb(row, c)));
                float ng = tanh_(gi[i][e] + binv + ar[i][j][e]*(gh[i][e] + bhnv));
                float zg = az_[i][j][e];
                float hn = (1.0f - zg)*ng + zg*hxv;
                *(ushort*)(F1 + swzb(row, c)) = f2bf(hn);
            }
    }
    __syncthreads();

    // ===== LayerNorm: F1(h_new) -> Hb(h_ln); coalesced fp32 h_new store =====
    {
        const int row = tid >> 3;         // 0..63, 8 threads/row
        const int o   = tid & 7;          // 32-col chunk
        bf16x8 ch[4];
        float sum = 0.0f, sq = 0.0f;
        #pragma unroll
        for (int c4 = 0; c4 < 4; ++c4) {
            ch[c4] = *(const bf16x8*)(F1 + swzb(row, o*32 + c4*8));
            #pragma unroll
            for (int e = 0; e < 8; ++e) {
                float f = b2f((ushort)ch[c4][e]);
                sum += f; sq += f*f;
            }
        }
        // coalesced h_new store (128B/thread contiguous)
        float* hp = hout + (size_t)(row0+row)*256 + o*32;
        #pragma unroll
        for (int c4 = 0; c4 < 4; ++c4) {
            float4 lo = { b2f((ushort)ch[c4][0]), b2f((ushort)ch[c4][1]),
                          b2f((ushort)ch[c4][2]), b2f((ushort)ch[c4][3]) };
            float4 hi = { b2f((ushort)ch[c4][4]), b2f((ushort)ch[c4][5]),
                          b2f((ushort)ch[c4][6]), b2f((ushort)ch[c4][7]) };
            *(float4*)(hp + c4*8)     = lo;
            *(float4*)(hp + c4*8 + 4) = hi;
        }
        sum += __shfl_xor(sum, 1); sum += __shfl_xor(sum, 2); sum += __shfl_xor(sum, 4);
        sq  += __shfl_xor(sq, 1);  sq  += __shfl_xor(sq, 2);  sq  += __shfl_xor(sq, 4);
        float mu   = sum * (1.0f/256.0f);
        float rstd = rsqrtf(sq*(1.0f/256.0f) - mu*mu + 1e-5f);
        #pragma unroll
        for (int c4 = 0; c4 < 4; ++c4) {
            int col0 = o*32 + c4*8;
            float4 g0 = *(const float4*)(ln_g + col0), g1 = *(const float4*)(ln_g + col0 + 4);
            float4 bb0 = *(const float4*)(ln_b + col0), bb1 = *(const float4*)(ln_b + col0 + 4);
            bf16x8 oo;
            oo[0] = (short)f2bf((b2f((ushort)ch[c4][0]) - mu)*rstd*g0.x + bb0.x);
            oo[1] = (short)f2bf((b2f((ushort)ch[c4][1]) - mu)*rstd*g0.y + bb0.y);
            oo[2] = (short)f2bf((b2f((ushort)ch[c4][2]) - mu)*rstd*g0.z + bb0.z);
            oo[3] = (short)f2bf((b2f((ushort)ch[c4][3]) - mu)*rstd*g0.w + bb0.w);
            oo[4] = (short)f2bf((b2f((ushort)ch[c4][4]) - mu)*rstd*g1.x + bb1.x);
            oo[5] = (short)f2bf((b2f((ushort)ch[c4][5]) - mu)*rstd*g1.y + bb1.y);
            oo[6] = (short)f2bf((b2f((ushort)ch[c4][6]) - mu)*rstd*g1.z + bb1.z);
            oo[7] = (short)f2bf((b2f((ushort)ch[c4][7]) - mu)*rstd*g1.w + bb1.w);
            *(bf16x8*)(Hb + swzb(row, col0)) = oo;
        }
    }
    __syncthreads();

    // ================= f1 = relu(W1 h_ln + b1): Hb -> F1 =================
    {
        f32x4 c2[2][4];
        #pragma unroll
        for (int i = 0; i < 2; ++i)
            #pragma unroll
            for (int j = 0; j < 4; ++j) c2[i][j] = (f32x4){0,0,0,0};
        const ushort* Bp = ws + OFF_W1 + (size_t)(nq*64 + lr)*SW1 + lk8;
        bf16x8 bc[4], bn[4];
        #pragma unroll
        for (int j = 0; j < 4; ++j) bc[j] = *(const bf16x8*)(Bp + j*16*SW1);
        #pragma unroll
        for (int kb = 0; kb < 8; ++kb) {
            if (kb < 7) {
                #pragma unroll
                for (int j = 0; j < 4; ++j) bn[j] = *(const bf16x8*)(Bp + j*16*SW1 + (kb+1)*32);
            }
            bf16x8 a0 = *(const bf16x8*)(Hb + swzb(mrow,      kb*32 + lk8));
            bf16x8 a1 = *(const bf16x8*)(Hb + swzb(mrow + 16, kb*32 + lk8));
            #pragma unroll
            for (int j = 0; j < 4; ++j) {
                c2[0][j] = __builtin_amdgcn_mfma_f32_16x16x32_bf16(a0, bc[j], c2[0][j], 0,0,0);
                c2[1][j] = __builtin_amdgcn_mfma_f32_16x16x32_bf16(a1, bc[j], c2[1][j], 0,0,0);
            }
            #pragma unroll
            for (int j = 0; j < 4; ++j) bc[j] = bn[j];
        }
        __syncthreads();   // Hb reads done before f2 overlays it? no — F1 write first; keep order: write F1 now
        #pragma unroll
        for (int j = 0; j < 4; ++j) {
            int c = nq*64 + j*16 + lr;
            float bv = b1[c];
            #pragma unroll
            for (int i = 0; i < 2; ++i)
                #pragma unroll
                for (int e = 0; e < 4; ++e) {
                    int row = mh*32 + i*16 + lk*4 + e;
                    *(ushort*)(F1 + swzb(row, c)) = f2bf(fmaxf(c2[i][j][e] + bv, 0.0f));
                }
        }
    }
    __syncthreads();

    // ================= f2 = relu(W2 f1 + b2): F1 -> F2 (overlay Hb) =================
    ushort* F2 = (ushort*)Hb;   // [64][136] bf16
    {
        f32x4 c3[2][2];
        #pragma unroll
        for (int i = 0; i < 2; ++i)
            #pragma unroll
            for (int j = 0; j < 2; ++j) c3[i][j] = (f32x4){0,0,0,0};
        const ushort* Bp = ws + OFF_W2 + (size_t)(nq*32 + lr)*SW2 + lk8;
        bf16x8 bc[2], bn[2];
        #pragma unroll
        for (int j = 0; j < 2; ++j) bc[j] = *(const bf16x8*)(Bp + j*16*SW2);
        #pragma unroll
        for (int kb = 0; kb < 8; ++kb) {
            if (kb < 7) {
                #pragma unroll
                for (int j = 0; j < 2; ++j) bn[j] = *(const bf16x8*)(Bp + j*16*SW2 + (kb+1)*32);
            }
            bf16x8 a0 = *(const bf16x8*)(F1 + swzb(mrow,      kb*32 + lk8));
            bf16x8 a1 = *(const bf16x8*)(F1 + swzb(mrow + 16, kb*32 + lk8));
            #pragma unroll
            for (int j = 0; j < 2; ++j) {
                c3[0][j] = __builtin_amdgcn_mfma_f32_16x16x32_bf16(a0, bc[j], c3[0][j], 0,0,0);
                c3[1][j] = __builtin_amdgcn_mfma_f32_16x16x32_bf16(a1, bc[j], c3[1][j], 0,0,0);
            }
            #pragma unroll
            for (int j = 0; j < 2; ++j) bc[j] = bn[j];
        }
        __syncthreads();  // all Hb(h_ln)... f2 A-reads from F1; ensure Hb free: f1 phase already synced. This sync orders F2 overlay after everyone's f2 A-loads? A is F1 — but F2 overlay writes Hb; waves still reading Hb? No: only f1 read Hb, already complete (sync above). Keep for write-order safety before overlay stores:
        #pragma unroll
        for (int j = 0; j < 2; ++j) {
            int c = nq*32 + j*16 + lr;
            float bv = b2[c];
            #pragma unroll
            for (int i = 0; i < 2; ++i)
                #pragma unroll
                for (int e = 0; e < 4; ++e) {
                    int row = mh*32 + i*16 + lk*4 + e;
                    F2[row*136 + c] = f2bf(fmaxf(c3[i][j][e] + bv, 0.0f));
                }
        }
    }
    __syncthreads();

    // ================= K = clip(W3 f2 + b3), correction =================
    {
        f32x4 c4[2][3];
        #pragma unroll
        for (int i = 0; i < 2; ++i)
            #pragma unroll
            for (int j = 0; j < 3; ++j) c4[i][j] = (f32x4){0,0,0,0};
        const int nfb = nq*3;
        const ushort* Bp = ws + OFF_W3 + (size_t)(nfb*16 + lr)*SW3 + lk8;
        bf16x8 bc[3], bn[3];
        #pragma unroll
        for (int j = 0; j < 3; ++j) bc[j] = *(const bf16x8*)(Bp + j*16*SW3);
        #pragma unroll
        for (int kb = 0; kb < 4; ++kb) {
            if (kb < 3) {
                #pragma unroll
                for (int j = 0; j < 3; ++j) bn[j] = *(const bf16x8*)(Bp + j*16*SW3 + (kb+1)*32);
            }
            bf16x8 a0 = *(const bf16x8*)(F2 + (mrow     )*136 + kb*32 + lk8);
            bf16x8 a1 = *(const bf16x8*)(F2 + (mrow + 16)*136 + kb*32 + lk8);
            #pragma unroll
            for (int j = 0; j < 3; ++j) {
                c4[0][j] = __builtin_amdgcn_mfma_f32_16x16x32_bf16(a0, bc[j], c4[0][j], 0,0,0);
                c4[1][j] = __builtin_amdgcn_mfma_f32_16x16x32_bf16(a1, bc[j], c4[1][j], 0,0,0);
            }
            #pragma unroll
            for (int j = 0; j < 3; ++j) bc[j] = bn[j];
        }
        #pragma unroll
        for (int j = 0; j < 3; ++j) {
            int col = (nfb+j)*16 + lr;
            if (col < 162) {
                int s = col / 27, m = col - s*27;
                float bv = b3[col];
                #pragma unroll
                for (int i = 0; i < 2; ++i)
                    #pragma unroll
                    for (int e = 0; e < 4; ++e) {
                        int row = mh*32 + i*16 + lk*4 + e;
                        float K  = fminf(fmaxf(c4[i][j][e] + bv, -3.0f), 3.0f);
                        float iv = b2f(Rb[row*RSTRIDE + m]);
                        atomicAdd(&xmc[row*6 + s], K*iv);
                    }
            }
        }
    }
    __syncthreads();

    for (int t = tid; t < ROWS*6; t += NTHR) {
        int row = t / 6, s = t - row*6;
        float v = fminf(fmaxf(xmc[t], -5.0f), 5.0f);
        out[(size_t)(row0+row)*6 + s] = v;
    }
}

extern "C" void kernel_launch(void* const* d_in, const int* in_sizes, int n_in,
                              void* d_out, int out_size, void* d_ws, size_t ws_size,
                              hipStream_t stream) {
    const float* meas      = (const float*)d_in[0];
    const float* mask      = (const float*)d_in[1];
    const float* dtv       = (const float*)d_in[2];
    const float* baselines = (const float*)d_in[3];
    const float* x_prev    = (const float*)d_in[4];
    const float* hx        = (const float*)d_in[5];
    const float* W_ih      = (const float*)d_in[6];
    const float* W_hh      = (const float*)d_in[7];
    const float* b_ih      = (const float*)d_in[8];
    const float* b_hh      = (const float*)d_in[9];
    const float* ln_g      = (const float*)d_in[10];
    const float* ln_b      = (const float*)d_in[11];
    const float* W1        = (const float*)d_in[12];
    const float* b1        = (const float*)d_in[13];
    const float* W2        = (const float*)d_in[14];
    const float* b2        = (const float*)d_in[15];
    const float* W3        = (const float*)d_in[16];
    const float* b3        = (const float*)d_in[17];
    ushort* wsb = (ushort*)d_ws;
    float* outp = (float*)d_out;

    prep_weights<<<(W_TOTAL + 255)/256, 256, 0, stream>>>(W_ih, W_hh, W1, W2, W3, wsb);
    knet_mfma<<<NWG, NTHR, LDS_TOTAL, stream>>>(
        meas, mask, dtv, baselines, x_prev, hx,
        b_ih, b_hh, ln_g, ln_b, b1, b2, b3, wsb, outp);
}

// Round 4
// 833.323 us; speedup vs baseline: 16.1362x; 1.3170x over previous
//
#include <hip/hip_runtime.h>
#include <math.h>

#define B_TOTAL  262144
#define ROWS     64
#define NWG      (B_TOTAL/ROWS)   // 4096
#define NTHR     512
#define PI_F     3.14159265358979323846f
#define NORM_R   (500.0f/150000.0f)

typedef float  f32x4  __attribute__((ext_vector_type(4)));
typedef short  bf16x8 __attribute__((ext_vector_type(8)));

// ---- bf16 weight workspace layout (ushort units) ----
#define SRZ 352   // [512][352]: k<73 = W_ih rows 0..511 ; k 96..351 = W_hh rows 0..511
#define SNI 96    // [256][96]:  W_ih rows 512..767 (n-gate input), k>=73 zero
#define SNH 256   // [256][256]: W_hh rows 512..767
#define SW1 256
#define SW2 256
#define SW3 128   // [256][128]: rows >=162 zero (padded to 256 for uniform staging)
#define OFF_RZ 0
#define OFF_NI (OFF_RZ + 512*SRZ)
#define OFF_NH (OFF_NI + 256*SNI)
#define OFF_W1 (OFF_NH + 256*SNH)
#define OFF_W2 (OFF_W1 + 256*SW1)
#define OFF_W3 (OFF_W2 + 128*SW2)
#define W_TOTAL (OFF_W3 + 256*SW3)  // 401408 ushort = 784 KiB

// ---- LDS layout (byte offsets), ROWS=64 ----
#define RSTRIDE 104
#define LDS_HB   (ROWS*RSTRIDE*2)          // Rb: [64][104] bf16           13312
#define LDS_F1   (LDS_HB + ROWS*256*2)     // Hb: [64][256] bf16 swizzled  32768
#define LDS_STG  (LDS_F1 + ROWS*256*2)     // F1: [64][256] bf16 swizzled  32768
#define LDS_XMC  (LDS_STG + 2*16384)       // STG: 2 x 16KB slice dbuf
#define LDS_TOTAL (LDS_XMC + ROWS*6*4)     // xmc: [64][6] f32  => 113152 B (1 WG/CU)

#define WAIT_VM2 asm volatile("s_waitcnt vmcnt(2)" ::: "memory")
#define WAIT_VM0 asm volatile("s_waitcnt vmcnt(0)" ::: "memory")
#define BARv     __builtin_amdgcn_s_barrier()

__device__ __forceinline__ ushort f2bf(float f){
    union { float f; unsigned u; } v; v.f = f;
    unsigned r = v.u + 0x7FFFu + ((v.u >> 16) & 1u);
    return (ushort)(r >> 16);
}
__device__ __forceinline__ float b2f(ushort u){
    union { unsigned u; float f; } v; v.u = ((unsigned)u) << 16;
    return v.f;
}
__device__ __forceinline__ float sigm(float x){ return 1.0f/(1.0f+__expf(-x)); }
__device__ __forceinline__ float tanh_(float x){ return 1.0f - 2.0f/(__expf(2.0f*x)+1.0f); }
__device__ __forceinline__ int swzb(int row, int k){          // [*][256] bf16, 16B-XOR swizzle
    return ((row<<9) + (k<<1)) ^ ((row&7)<<4);
}

// stage a 16KB slice: 256 cols x 64B (32 k-elems), XOR-swizzled k-chunks.
// LDS dest linear (wave-uniform base + lane*16); source pre-swizzled (G21).
__device__ __forceinline__ void stageA(const ushort* pb, int stride, int koff,
                                       char* dst, int w, int lane) {
    #pragma unroll
    for (int i = 0; i < 2; ++i) {
        int idx  = (w*2 + i)*64 + lane;        // 0..1023
        int col  = idx >> 2;
        int kq   = (idx & 3) ^ ((col >> 1) & 3);
        const ushort* g = pb + (size_t)col*stride + koff + kq*8;
        __builtin_amdgcn_global_load_lds(
            (const __attribute__((address_space(1))) void*)g,
            (__attribute__((address_space(3))) void*)(dst + (w*2+i)*1024),
            16, 0, 0);
    }
}
// stage a 16KB slice: 128 cols x 128B (64 k-elems)
__device__ __forceinline__ void stageB(const ushort* pb, int stride, int koff,
                                       char* dst, int w, int lane) {
    #pragma unroll
    for (int i = 0; i < 2; ++i) {
        int idx  = (w*2 + i)*64 + lane;
        int col  = idx >> 3;
        int kq   = (idx & 7) ^ (col & 7);
        const ushort* g = pb + (size_t)col*stride + koff + kq*8;
        __builtin_amdgcn_global_load_lds(
            (const __attribute__((address_space(1))) void*)g,
            (__attribute__((address_space(3))) void*)(dst + (w*2+i)*1024),
            16, 0, 0);
    }
}
__device__ __forceinline__ bf16x8 rdA16(const char* sb, int col, int lk){
    int slot = lk ^ ((col >> 1) & 3);
    return *(const bf16x8*)(sb + col*64 + slot*16);
}
__device__ __forceinline__ bf16x8 rdB16(const char* sb, int col, int ksub, int lk){
    int slot = ((ksub<<2)|lk) ^ (col & 7);
    return *(const bf16x8*)(sb + col*128 + slot*16);
}

__global__ void prep_weights(const float* __restrict__ W_ih, const float* __restrict__ W_hh,
                             const float* __restrict__ W1, const float* __restrict__ W2,
                             const float* __restrict__ W3, ushort* __restrict__ ws)
{
    int id = blockIdx.x*256 + threadIdx.x;
    if (id >= W_TOTAL) return;
    float v = 0.0f;
    if (id < OFF_NI) {
        int t = id; int n = t / SRZ, k = t - n*SRZ;
        if (k < 73) v = W_ih[n*73 + k];
        else if (k >= 96) v = W_hh[n*256 + (k-96)];
    } else if (id < OFF_NH) {
        int t = id - OFF_NI; int n = t / SNI, k = t - n*SNI;
        if (k < 73) v = W_ih[(512+n)*73 + k];
    } else if (id < OFF_W1) {
        int t = id - OFF_NH; int n = t >> 8, k = t & 255;
        v = W_hh[(512+n)*256 + k];
    } else if (id < OFF_W2) {
        int t = id - OFF_W1; int n = t >> 8, k = t & 255;
        v = W1[n*256 + k];
    } else if (id < OFF_W3) {
        int t = id - OFF_W2; int n = t >> 8, k = t & 255;
        v = W2[n*256 + k];
    } else {
        int t = id - OFF_W3; int n = t >> 7, k = t & 127;
        if (n < 162) v = W3[n*128 + k];
    }
    ws[id] = f2bf(v);
}

__global__ __launch_bounds__(NTHR, 2) void knet_mfma(
    const float* __restrict__ meas, const float* __restrict__ mask,
    const float* __restrict__ dt,   const float* __restrict__ baselines,
    const float* __restrict__ x_prev, const float* __restrict__ hx,
    const float* __restrict__ b_ih, const float* __restrict__ b_hh,
    const float* __restrict__ ln_g, const float* __restrict__ ln_b,
    const float* __restrict__ b1,   const float* __restrict__ b2,
    const float* __restrict__ b3,
    const ushort* __restrict__ ws,
    float* __restrict__ out)
{
    extern __shared__ char smem[];
    ushort* Rb  = (ushort*)smem;
    char*   Hb  = smem + LDS_HB;
    char*   F1  = smem + LDS_F1;
    char*   STG = smem + LDS_STG;
    float*  xmc = (float*)(smem + LDS_XMC);

    const int tid  = threadIdx.x;
    const int w    = __builtin_amdgcn_readfirstlane(tid >> 6);
    const int nq   = w & 3;
    const int mh   = w >> 2;
    const int lane = tid & 63;
    const int lr   = lane & 15;
    const int lk   = lane >> 4;
    const int lk8  = lk * 8;
    const int row0 = blockIdx.x * ROWS;
    const int mrow = mh*32 + lr;
    float* hout = out + (size_t)B_TOTAL*6;

    // prologue: stage slice 0 (r-gate kb0) into buf0, earliest possible
    stageA(ws + OFF_RZ, SRZ, 0, STG, w, lane);

    // ================= stage inputs =================
    {
        const int part = w;
        const int row  = lane;
        const int gb   = row0 + row;
        if (part < 4) {
            const float dtv = dt[gb];
            const float dts = dtv * NORM_R;
            float xp[6], xm[6];
            #pragma unroll
            for (int s = 0; s < 6; ++s) xp[s] = x_prev[(size_t)gb*6 + s];
            xm[0] = xp[0] + dts*xp[1]; xm[1] = xp[1];
            xm[2] = xp[2] + dts*xp[3]; xm[3] = xp[3];
            xm[4] = xp[4] + dts*xp[5]; xm[5] = xp[5];
            if (part < 3) {
                float xr[6];
                #pragma unroll
                for (int s = 0; s < 6; ++s) {
                    float b = (part == 0) ? 0.0f : baselines[(size_t)gb*12 + (part-1)*6 + s];
                    xr[s] = xm[s] - b;
                }
                float rxy = sqrtf(xr[0]*xr[0] + xr[2]*xr[2] + 1e-9f);
                float azv = atan2f(xr[2], xr[0]) * (1.0f/PI_F);
                float elv = atan2f(xr[4], rxy)   * (1.0f/PI_F);
                float rrv = sqrtf(xr[0]*xr[0] + xr[2]*xr[2] + xr[4]*xr[4] + 1e-9f);
                float y[9] = {azv, elv, rrv, azv, elv, 0.0f, azv, 0.0f, 0.0f};
                const bool ang[9] = {true,true,false,true,true,false,true,false,false};
                #pragma unroll
                for (int i = 0; i < 9; ++i) {
                    int m = part*9 + i;
                    float ms = mask[(size_t)gb*27 + m];
                    float v  = meas[(size_t)gb*27 + m] - y[i];
                    if (ang[i]) v = v - 2.0f*rintf(v*0.5f);
                    v *= ms;
                    Rb[row*RSTRIDE + m]      = f2bf(v);
                    Rb[row*RSTRIDE + 27 + m] = f2bf(ms);
                }
            } else {
                Rb[row*RSTRIDE + 54] = f2bf(dtv);
                #pragma unroll
                for (int s = 0; s < 6; ++s) Rb[row*RSTRIDE + 55 + s] = f2bf(xm[s]);
                #pragma unroll
                for (int q = 0; q < 12; ++q) Rb[row*RSTRIDE + 61 + q] = f2bf(baselines[(size_t)gb*12 + q]);
                #pragma unroll
                for (int k = 73; k < 96; ++k) Rb[row*RSTRIDE + k] = 0;
                #pragma unroll
                for (int s = 0; s < 6; ++s) xmc[row*6 + s] = xm[s];
            }
        }
        const size_t hbase = (size_t)row0 * 256;
        #pragma unroll
        for (int ii = 0; ii < 4; ++ii) {
            int cid = tid + ii*NTHR;
            int r  = cid >> 5;
            int k0 = (cid & 31) << 3;
            const float4* p = (const float4*)(hx + hbase + (size_t)r*256 + k0);
            float4 u = p[0], v2 = p[1];
            bf16x8 o;
            o[0]=(short)f2bf(u.x);  o[1]=(short)f2bf(u.y);  o[2]=(short)f2bf(u.z);  o[3]=(short)f2bf(u.w);
            o[4]=(short)f2bf(v2.x); o[5]=(short)f2bf(v2.y); o[6]=(short)f2bf(v2.z); o[7]=(short)f2bf(v2.w);
            *(bf16x8*)(Hb + swzb(r, k0)) = o;
        }
    }
    __syncthreads();

    // ======== pipelined slice loop: r(11) z(11) NI(3) NH(8), slices 0..32 ========
    f32x4 ar[2][4], az_[2][4], gi[2][4], gh[2][4];
    #pragma unroll
    for (int i = 0; i < 2; ++i)
        #pragma unroll
        for (int j = 0; j < 4; ++j) {
            ar[i][j]=(f32x4){0,0,0,0}; az_[i][j]=(f32x4){0,0,0,0};
            gi[i][j]=(f32x4){0,0,0,0}; gh[i][j]=(f32x4){0,0,0,0};
        }

    // ---- r pass: slices 0..10
    for (int kb = 0; kb < 11; ++kb) {
        char* nb = STG + (((kb+1)&1)<<14);
        if (kb < 10) stageA(ws + OFF_RZ, SRZ, (kb+1)*32, nb, w, lane);
        else         stageA(ws + OFF_RZ + (size_t)256*SRZ, SRZ, 0, nb, w, lane);
        WAIT_VM2; BARv;
        char* sb = STG + ((kb&1)<<14);
        bf16x8 a0, a1;
        if (kb < 3) { a0 = *(const bf16x8*)(Rb + mrow*RSTRIDE + kb*32 + lk8);
                      a1 = *(const bf16x8*)(Rb + (mrow+16)*RSTRIDE + kb*32 + lk8); }
        else        { a0 = *(const bf16x8*)(Hb + swzb(mrow,    (kb-3)*32 + lk8));
                      a1 = *(const bf16x8*)(Hb + swzb(mrow+16, (kb-3)*32 + lk8)); }
        __builtin_amdgcn_s_setprio(1);
        #pragma unroll
        for (int j = 0; j < 4; ++j) {
            bf16x8 b = rdA16(sb, nq*64 + j*16 + lr, lk);
            ar[0][j] = __builtin_amdgcn_mfma_f32_16x16x32_bf16(a0, b, ar[0][j], 0,0,0);
            ar[1][j] = __builtin_amdgcn_mfma_f32_16x16x32_bf16(a1, b, ar[1][j], 0,0,0);
        }
        __builtin_amdgcn_s_setprio(0);
        BARv;
    }
    // ---- z pass: slices 11..21
    for (int kb = 0; kb < 11; ++kb) {
        char* nb = STG + (((kb)&1)<<14);       // slice 11+kb parity = (11+kb)&1; next = (12+kb)&1 = kb&1
        if (kb < 10) stageA(ws + OFF_RZ + (size_t)256*SRZ, SRZ, (kb+1)*32, nb, w, lane);
        else         stageA(ws + OFF_NI, SNI, 0, nb, w, lane);
        WAIT_VM2; BARv;
        char* sb = STG + (((kb+1)&1)<<14);     // (11+kb)&1
        bf16x8 a0, a1;
        if (kb < 3) { a0 = *(const bf16x8*)(Rb + mrow*RSTRIDE + kb*32 + lk8);
                      a1 = *(const bf16x8*)(Rb + (mrow+16)*RSTRIDE + kb*32 + lk8); }
        else        { a0 = *(const bf16x8*)(Hb + swzb(mrow,    (kb-3)*32 + lk8));
                      a1 = *(const bf16x8*)(Hb + swzb(mrow+16, (kb-3)*32 + lk8)); }
        __builtin_amdgcn_s_setprio(1);
        #pragma unroll
        for (int j = 0; j < 4; ++j) {
            bf16x8 b = rdA16(sb, nq*64 + j*16 + lr, lk);
            az_[0][j] = __builtin_amdgcn_mfma_f32_16x16x32_bf16(a0, b, az_[0][j], 0,0,0);
            az_[1][j] = __builtin_amdgcn_mfma_f32_16x16x32_bf16(a1, b, az_[1][j], 0,0,0);
        }
        __builtin_amdgcn_s_setprio(0);
        BARv;
    }
    // ---- n gate: NI slices 22..24, NH slices 25..32
    for (int s = 0; s < 11; ++s) {
        char* nb = STG + (((s+23)&1)<<14);
        if (s < 2)       stageA(ws + OFF_NI, SNI, (s+1)*32, nb, w, lane);
        else if (s < 10) stageA(ws + OFF_NH, SNH, (s-2)*32, nb, w, lane);
        else             stageA(ws + OFF_W1, SW1, 0,        nb, w, lane);  // f1 slice 33
        WAIT_VM2; BARv;
        char* sb = STG + (((s+22)&1)<<14);
        bf16x8 a0, a1;
        if (s < 3) { a0 = *(const bf16x8*)(Rb + mrow*RSTRIDE + s*32 + lk8);
                     a1 = *(const bf16x8*)(Rb + (mrow+16)*RSTRIDE + s*32 + lk8); }
        else       { a0 = *(const bf16x8*)(Hb + swzb(mrow,    (s-3)*32 + lk8));
                     a1 = *(const bf16x8*)(Hb + swzb(mrow+16, (s-3)*32 + lk8)); }
        __builtin_amdgcn_s_setprio(1);
        if (s < 3) {
            #pragma unroll
            for (int j = 0; j < 4; ++j) {
                bf16x8 b = rdA16(sb, nq*64 + j*16 + lr, lk);
                gi[0][j] = __builtin_amdgcn_mfma_f32_16x16x32_bf16(a0, b, gi[0][j], 0,0,0);
                gi[1][j] = __builtin_amdgcn_mfma_f32_16x16x32_bf16(a1, b, gi[1][j], 0,0,0);
            }
        } else {
            #pragma unroll
            for (int j = 0; j < 4; ++j) {
                bf16x8 b = rdA16(sb, nq*64 + j*16 + lr, lk);
                gh[0][j] = __builtin_amdgcn_mfma_f32_16x16x32_bf16(a0, b, gh[0][j], 0,0,0);
                gh[1][j] = __builtin_amdgcn_mfma_f32_16x16x32_bf16(a1, b, gh[1][j], 0,0,0);
            }
        }
        __builtin_amdgcn_s_setprio(0);
        BARv;
    }
    // ---- GRU epilogue: h_new -> F1 (bf16)
    #pragma unroll
    for (int j = 0; j < 4; ++j) {
        int c = nq*64 + j*16 + lr;
        float brv = b_ih[c] + b_hh[c];
        float bzv = b_ih[256+c] + b_hh[256+c];
        float binv = b_ih[512+c], bhnv = b_hh[512+c];
        #pragma unroll
        for (int i = 0; i < 2; ++i)
            #pragma unroll
            for (int e = 0; e < 4; ++e) {
                int row = mh*32 + i*16 + lk*4 + e;
                float rg = sigm(ar[i][j][e] + brv);
                float zg = sigm(az_[i][j][e] + bzv);
                float ng = tanh_(gi[i][j][e] + binv + rg*(gh[i][j][e] + bhnv));
                float hxv = b2f(*(const ushort*)(Hb + swzb(row, c)));
                float hn = (1.0f - zg)*ng + zg*hxv;
                *(ushort*)(F1 + swzb(row, c)) = f2bf(hn);
            }
    }
    __syncthreads();

    // ===== LayerNorm: F1(h_new) -> Hb(h_ln), + lane-contiguous h_new store =====
    {
        const int row = tid >> 3;
        const int o   = tid & 7;
        bf16x8 ch[4];
        float sum = 0.0f, sq = 0.0f;
        #pragma unroll
        for (int c4 = 0; c4 < 4; ++c4) {
            ch[c4] = *(const bf16x8*)(F1 + swzb(row, o*32 + c4*8));
            #pragma unroll
            for (int e = 0; e < 8; ++e) {
                float f = b2f((ushort)ch[c4][e]);
                sum += f; sq += f*f;
            }
        }
        sum += __shfl_xor(sum, 1); sum += __shfl_xor(sum, 2); sum += __shfl_xor(sum, 4);
        sq  += __shfl_xor(sq, 1);  sq  += __shfl_xor(sq, 2);  sq  += __shfl_xor(sq, 4);
        float mu   = sum * (1.0f/256.0f);
        float rstd = rsqrtf(sq*(1.0f/256.0f) - mu*mu + 1e-5f);
        #pragma unroll
        for (int c4 = 0; c4 < 4; ++c4) {
            int col0 = o*32 + c4*8;
            float4 g0 = *(const float4*)(ln_g + col0), g1 = *(const float4*)(ln_g + col0 + 4);
            float4 bb0 = *(const float4*)(ln_b + col0), bb1 = *(const float4*)(ln_b + col0 + 4);
            bf16x8 oo;
            oo[0] = (short)f2bf((b2f((ushort)ch[c4][0]) - mu)*rstd*g0.x + bb0.x);
            oo[1] = (short)f2bf((b2f((ushort)ch[c4][1]) - mu)*rstd*g0.y + bb0.y);
            oo[2] = (short)f2bf((b2f((ushort)ch[c4][2]) - mu)*rstd*g0.z + bb0.z);
            oo[3] = (short)f2bf((b2f((ushort)ch[c4][3]) - mu)*rstd*g0.w + bb0.w);
            oo[4] = (short)f2bf((b2f((ushort)ch[c4][4]) - mu)*rstd*g1.x + bb1.x);
            oo[5] = (short)f2bf((b2f((ushort)ch[c4][5]) - mu)*rstd*g1.y + bb1.y);
            oo[6] = (short)f2bf((b2f((ushort)ch[c4][6]) - mu)*rstd*g1.z + bb1.z);
            oo[7] = (short)f2bf((b2f((ushort)ch[c4][7]) - mu)*rstd*g1.w + bb1.w);
            *(bf16x8*)(Hb + swzb(row, col0)) = oo;
        }
        // lane-contiguous fp32 h_new store: per instr, lanes cover contiguous 1KB
        #pragma unroll
        for (int i = 0; i < 8; ++i) {
            int chunk = i*NTHR + tid;           // 0..4095
            int r2 = chunk >> 6;
            int c16 = chunk & 63;
            uint2 d = *(const uint2*)(F1 + swzb(r2, c16*4));
            float4 o4;
            o4.x = b2f((ushort)(d.x & 0xffffu)); o4.y = b2f((ushort)(d.x >> 16));
            o4.z = b2f((ushort)(d.y & 0xffffu)); o4.w = b2f((ushort)(d.y >> 16));
            *(float4*)(hout + (size_t)(row0+r2)*256 + c16*4) = o4;
        }
    }
    __syncthreads();

    // ================= f1 = relu(W1 h_ln + b1): Hb -> F1, slices 33..40 =================
    {
        f32x4 c2[2][4];
        #pragma unroll
        for (int i = 0; i < 2; ++i)
            #pragma unroll
            for (int j = 0; j < 4; ++j) c2[i][j] = (f32x4){0,0,0,0};
        for (int kb = 0; kb < 8; ++kb) {
            char* nb = STG + (((kb+34)&1)<<14);
            if (kb < 7) stageA(ws + OFF_W1, SW1, (kb+1)*32, nb, w, lane);
            else        stageB(ws + OFF_W2, SW2, 0,         nb, w, lane);  // f2 slice 41
            WAIT_VM2; BARv;
            char* sb = STG + (((kb+33)&1)<<14);
            bf16x8 a0 = *(const bf16x8*)(Hb + swzb(mrow,    kb*32 + lk8));
            bf16x8 a1 = *(const bf16x8*)(Hb + swzb(mrow+16, kb*32 + lk8));
            __builtin_amdgcn_s_setprio(1);
            #pragma unroll
            for (int j = 0; j < 4; ++j) {
                bf16x8 b = rdA16(sb, nq*64 + j*16 + lr, lk);
                c2[0][j] = __builtin_amdgcn_mfma_f32_16x16x32_bf16(a0, b, c2[0][j], 0,0,0);
                c2[1][j] = __builtin_amdgcn_mfma_f32_16x16x32_bf16(a1, b, c2[1][j], 0,0,0);
            }
            __builtin_amdgcn_s_setprio(0);
            BARv;
        }
        #pragma unroll
        for (int j = 0; j < 4; ++j) {
            int c = nq*64 + j*16 + lr;
            float bv = b1[c];
            #pragma unroll
            for (int i = 0; i < 2; ++i)
                #pragma unroll
                for (int e = 0; e < 4; ++e) {
                    int row = mh*32 + i*16 + lk*4 + e;
                    *(ushort*)(F1 + swzb(row, c)) = f2bf(fmaxf(c2[i][j][e] + bv, 0.0f));
                }
        }
    }
    __syncthreads();

    // ================= f2 = relu(W2 f1 + b2): F1 -> F2 (overlay Hb), slices 41..44 =================
    ushort* F2 = (ushort*)Hb;   // [64][136] bf16
    {
        f32x4 c3[2][2];
        #pragma unroll
        for (int i = 0; i < 2; ++i)
            #pragma unroll
            for (int j = 0; j < 2; ++j) c3[i][j] = (f32x4){0,0,0,0};
        for (int kb = 0; kb < 4; ++kb) {
            char* nb = STG + (((kb+42)&1)<<14);
            if (kb < 3) stageB(ws + OFF_W2, SW2, (kb+1)*64, nb, w, lane);
            else        stageA(ws + OFF_W3, SW3, 0,         nb, w, lane);  // w3 slice 45
            WAIT_VM2; BARv;
            char* sb = STG + (((kb+41)&1)<<14);
            __builtin_amdgcn_s_setprio(1);
            #pragma unroll
            for (int ksub = 0; ksub < 2; ++ksub) {
                bf16x8 a0 = *(const bf16x8*)(F1 + swzb(mrow,    kb*64 + ksub*32 + lk8));
                bf16x8 a1 = *(const bf16x8*)(F1 + swzb(mrow+16, kb*64 + ksub*32 + lk8));
                #pragma unroll
                for (int j = 0; j < 2; ++j) {
                    bf16x8 b = rdB16(sb, nq*32 + j*16 + lr, ksub, lk);
                    c3[0][j] = __builtin_amdgcn_mfma_f32_16x16x32_bf16(a0, b, c3[0][j], 0,0,0);
                    c3[1][j] = __builtin_amdgcn_mfma_f32_16x16x32_bf16(a1, b, c3[1][j], 0,0,0);
                }
            }
            __builtin_amdgcn_s_setprio(0);
            BARv;
        }
        __syncthreads();   // all F1 reads + Hb(h_ln) fully dead before overlay write
        #pragma unroll
        for (int j = 0; j < 2; ++j) {
            int c = nq*32 + j*16 + lr;
            float bv = b2[c];
            #pragma unroll
            for (int i = 0; i < 2; ++i)
                #pragma unroll
                for (int e = 0; e < 4; ++e) {
                    int row = mh*32 + i*16 + lk*4 + e;
                    F2[row*136 + c] = f2bf(fmaxf(c3[i][j][e] + bv, 0.0f));
                }
        }
    }
    __syncthreads();

    // ================= K = clip(W3 f2 + b3): slices 45..48, einsum =================
    {
        f32x4 c4[2][3];
        #pragma unroll
        for (int i = 0; i < 2; ++i)
            #pragma unroll
            for (int j = 0; j < 3; ++j) c4[i][j] = (f32x4){0,0,0,0};
        const int nfb = nq*3;
        for (int kb = 0; kb < 4; ++kb) {
            char* nb = STG + (((kb+46)&1)<<14);
            if (kb < 3) { stageA(ws + OFF_W3, SW3, (kb+1)*32, nb, w, lane); WAIT_VM2; }
            else        { WAIT_VM0; }
            BARv;
            char* sb = STG + (((kb+45)&1)<<14);
            bf16x8 a0 = *(const bf16x8*)(F2 + (mrow     )*136 + kb*32 + lk8);
            bf16x8 a1 = *(const bf16x8*)(F2 + (mrow + 16)*136 + kb*32 + lk8);
            __builtin_amdgcn_s_setprio(1);
            #pragma unroll
            for (int j = 0; j < 3; ++j) {
                bf16x8 b = rdA16(sb, (nfb+j)*16 + lr, lk);
                c4[0][j] = __builtin_amdgcn_mfma_f32_16x16x32_bf16(a0, b, c4[0][j], 0,0,0);
                c4[1][j] = __builtin_amdgcn_mfma_f32_16x16x32_bf16(a1, b, c4[1][j], 0,0,0);
            }
            __builtin_amdgcn_s_setprio(0);
            BARv;
        }
        #pragma unroll
        for (int j = 0; j < 3; ++j) {
            int col = (nfb+j)*16 + lr;
            if (col < 162) {
                int s = col / 27, m = col - s*27;
                float bv = b3[col];
                #pragma unroll
                for (int i = 0; i < 2; ++i)
                    #pragma unroll
                    for (int e = 0; e < 4; ++e) {
                        int row = mh*32 + i*16 + lk*4 + e;
                        float K  = fminf(fmaxf(c4[i][j][e] + bv, -3.0f), 3.0f);
                        float iv = b2f(Rb[row*RSTRIDE + m]);
                        atomicAdd(&xmc[row*6 + s], K*iv);
                    }
            }
        }
    }
    __syncthreads();

    for (int t = tid; t < ROWS*6; t += NTHR) {
        int row = t / 6, s = t - row*6;
        float v = fminf(fmaxf(xmc[t], -5.0f), 5.0f);
        out[(size_t)(row0+row)*6 + s] = v;
    }
}

extern "C" void kernel_launch(void* const* d_in, const int* in_sizes, int n_in,
                              void* d_out, int out_size, void* d_ws, size_t ws_size,
                              hipStream_t stream) {
    const float* meas      = (const float*)d_in[0];
    const float* mask      = (const float*)d_in[1];
    const float* dtv       = (const float*)d_in[2];
    const float* baselines = (const float*)d_in[3];
    const float* x_prev    = (const float*)d_in[4];
    const float* hx        = (const float*)d_in[5];
    const float* W_ih      = (const float*)d_in[6];
    const float* W_hh      = (const float*)d_in[7];
    const float* b_ih      = (const float*)d_in[8];
    const float* b_hh      = (const float*)d_in[9];
    const float* ln_g      = (const float*)d_in[10];
    const float* ln_b      = (const float*)d_in[11];
    const float* W1        = (const float*)d_in[12];
    const float* b1        = (const float*)d_in[13];
    const float* W2        = (const float*)d_in[14];
    const float* b2        = (const float*)d_in[15];
    const float* W3        = (const float*)d_in[16];
    const float* b3        = (const float*)d_in[17];
    ushort* wsb = (ushort*)d_ws;
    float* outp = (float*)d_out;

    prep_weights<<<(W_TOTAL + 255)/256, 256, 0, stream>>>(W_ih, W_hh, W1, W2, W3, wsb);
    knet_mfma<<<NWG, NTHR, LDS_TOTAL, stream>>>(
        meas, mask, dtv, baselines, x_prev, hx,
        b_ih, b_hh, ln_g, ln_b, b1, b2, b3, wsb, outp);
}